// Round 2
// baseline (2012.602 us; speedup 1.0000x reference)
//
#include <hip/hip_runtime.h>

typedef unsigned short ushort_t;
typedef __bf16 bf16x8 __attribute__((ext_vector_type(8)));
typedef float f32x4 __attribute__((ext_vector_type(4)));

#define PACK_W_ELEMS (64*9*64*8)   // 294912 bf16 per LSTM (64 n-tiles x 9 k-tiles x 64 lanes x 8)
#define FLAG_OFS (4*PACK_W_ELEMS + 8192 + 8192)  // ushort offset of the int dtype flag

__device__ __forceinline__ float bf2f(ushort_t u){ return __uint_as_float(((unsigned)u)<<16); }
__device__ __forceinline__ ushort_t f2bf(float f){
  unsigned u = __float_as_uint(f);
  if ((u & 0x7fffffffu) > 0x7f800000u) return (ushort_t)0x7fc0;  // NaN guard
  u += 0x7fffu + ((u>>16)&1u);      // round-to-nearest-even
  return (ushort_t)(u>>16);
}
__device__ __forceinline__ float sigmf_(float x){ return 1.0f/(1.0f + __expf(-x)); }
__device__ __forceinline__ float tanhf_(float x){ return 1.0f - 2.0f/(1.0f + __expf(2.0f*x)); }

// dtype sniff: bf16 arrays have EVERY ushort a plausible small bf16; fp32 arrays have
// mantissa-random even ushorts (P(all 32 probes in (-8,8)) ~ 4e-10).
__device__ __forceinline__ int sniff_f32(const ushort_t* w){
  int f32 = 0;
  #pragma unroll
  for (int i = 0; i < 32; ++i){
    float f = bf2f(w[2*i]);
    if (!(f > -8.f && f < 8.f)) f32 = 1;
  }
  return f32;
}
__device__ __forceinline__ float ldin(const ushort_t* p, int i, int f32){
  return f32 ? ((const float*)p)[i] : bf2f(p[i]);
}
__device__ __forceinline__ ushort_t ldw(const ushort_t* p, int i, int f32){
  return f32 ? f2bf(((const float*)p)[i]) : p[i];
}

// ---------------- pack kernel: weights -> MFMA B-fragment layout in ws ----------------
// ws layout (ushort units):
//   [0, 4*PACK_W_ELEMS)          : packed [Whh|Wih|0] per LSTM (sp, po, dsp, dcr), K=288, N=1024
//   [+0, +4096)                  : speed head pack  (N=16: fc_speed rows 0..3, rest 0; K=256)
//   [+4096, +8192)               : cross head pack  (N: 0..3 emb, 4..5 fc_cross, rest 0)
//   [+8192, +16384) as float[4][1024] : bias sums (bih+bhh) fp32
//   [FLAG_OFS] as int            : 1 if inputs are fp32, 0 if bf16
struct PackArgs {
  const ushort_t* wih[4]; const ushort_t* whh[4];
  const ushort_t* bih[4]; const ushort_t* bhh[4];
  const ushort_t* fcsp_w; const ushort_t* fccr_w; const ushort_t* emb_w;
  ushort_t* ws;
};

__global__ void pack_kernel(PackArgs a){
  const int f32 = sniff_f32(a.whh[0]);
  int idx = blockIdx.x*256 + threadIdx.x;
  if (blockIdx.x == 0 && threadIdx.x == 0) *(int*)(a.ws + FLAG_OFS) = f32;
  const int total_w = 4*PACK_W_ELEMS;
  if (idx < total_w){
    int l = idx / PACK_W_ELEMS;
    int r = idx % PACK_W_ELEMS;
    int j = r & 7;
    int lane = (r>>3) & 63;
    int tile = r >> 9;            // ntg*9 + kt
    int kt = tile % 9;
    int ntg = tile / 9;
    int n = ntg*16 + (lane & 15);
    int k = kt*32 + ((lane>>4)<<3) + j;
    ushort_t v = 0;
    if (k < 256)      v = ldw(a.whh[l], n*256 + k, f32);
    else if (k < 260) v = ldw(a.wih[l], n*4 + (k-256), f32);
    a.ws[l*PACK_W_ELEMS + r] = v;
    return;
  }
  idx -= total_w;
  if (idx < 4096){
    int j = idx & 7; int lane = (idx>>3)&63; int kt = idx>>9;
    int n = lane & 15; int k = kt*32 + ((lane>>4)<<3) + j;
    ushort_t v = 0;
    if (n < 4) v = ldw(a.fcsp_w, n*256 + k, f32);
    a.ws[total_w + idx] = v; return;
  }
  idx -= 4096;
  if (idx < 4096){
    int j = idx & 7; int lane = (idx>>3)&63; int kt = idx>>9;
    int n = lane & 15; int k = kt*32 + ((lane>>4)<<3) + j;
    ushort_t v = 0;
    if (n < 4)      v = ldw(a.emb_w, n*256 + k, f32);
    else if (n < 6) v = ldw(a.fccr_w, (n-4)*256 + k, f32);
    a.ws[total_w + 4096 + idx] = v; return;
  }
  idx -= 4096;
  if (idx < 4096){
    int l = idx >> 10; int n = idx & 1023;
    float* bs = (float*)(a.ws + total_w + 8192);
    bs[l*1024 + n] = ldin(a.bih[l], n, f32) + ldin(a.bhh[l], n, f32);
  }
}

// ---------------- main kernel: 256 blocks x 64 batch rows, all 4 phases ----------------
__global__ __launch_bounds__(512, 2) void pvlstm_main(
    const ushort_t* __restrict__ ws,
    const ushort_t* __restrict__ speed,
    const ushort_t* __restrict__ pos,
    const ushort_t* __restrict__ fcsp_b,
    const ushort_t* __restrict__ fccr_b,
    const ushort_t* __restrict__ embb,
    void* __restrict__ outv)
{
  // A-pack: [4 m-tiles][9 k-tiles][512] bf16 in exact MFMA A-frag order (36 KB)
  __shared__ ushort_t Ap[4*9*512];
  __shared__ ushort_t h0s[64*256];   // h0 = h_sp + h_po (bf16, 32 KB)
  __shared__ float    c0s[64*256];   // c0 = c_sp + c_po (fp32, 64 KB)

  const int f32   = *(const int*)(ws + FLAG_OFS);
  const int tid   = threadIdx.x;
  const int lane  = tid & 63;
  const int wid   = tid >> 6;   // 0..7
  const int mh    = wid >> 2;   // m-half
  const int cr    = wid & 3;    // hidden col-range (64 cols)
  const int col16 = lane & 15;
  const int quad  = lane >> 4;
  const int brow0 = blockIdx.x * 64;

  ushort_t* outu = (ushort_t*)outv;
  float*    outf = (float*)outv;

  const ushort_t* headsp  = ws + 4*PACK_W_ELEMS;
  const ushort_t* headcr  = headsp + 4096;
  const float* bias_all   = (const float*)(ws + 4*PACK_W_ELEMS + 8192);

  const f32x4 zero4 = {0.f, 0.f, 0.f, 0.f};
  float cw[2][4][4];   // working cell state (C-layout per lane)

  for (int phase = 0; phase < 4; ++phase){
    const ushort_t* packW = ws + phase*PACK_W_ELEMS;
    const float* bias = bias_all + phase*1024;
    const ushort_t* seq = (phase & 1) ? pos : speed;  // 0:sp 1:po 2:sp 3:po
    const bool is_enc = (phase < 2);
    const ushort_t* headW = (phase == 2) ? headsp : headcr;

    float bia[4][4];
    #pragma unroll
    for (int g = 0; g < 4; ++g)
      #pragma unroll
      for (int ht = 0; ht < 4; ++ht)
        bia[g][ht] = bias[g*256 + cr*64 + ht*16 + col16];

    __syncthreads();
    if (is_enc){
      // h := 0 (zero whole A-pack; x-slot padding stays zero), c := 0
      for (int i = tid; i < 4*9*512/2; i += 512) ((unsigned*)Ap)[i] = 0u;
      #pragma unroll
      for (int ml = 0; ml < 2; ++ml)
        #pragma unroll
        for (int ht = 0; ht < 4; ++ht)
          #pragma unroll
          for (int r = 0; r < 4; ++r) cw[ml][ht][r] = 0.f;
    } else {
      // h := h0 (bf16 copy into A-frag layout), x0 := seq[:,15,:], c := c0
      for (int i = tid; i < 64*256; i += 512){
        int m = i >> 8, col = i & 255;
        Ap[((m>>4)*9 + (col>>5))*512 + ((col>>3)&3)*128 + (m&15)*8 + (col&7)] = h0s[i];
      }
      if (tid < 64){
        const int base = (brow0+tid)*64 + 60;
        ushort_t* xp = &Ap[((tid>>4)*9 + 8)*512 + (tid&15)*8];
        #pragma unroll
        for (int s2 = 0; s2 < 4; ++s2) xp[s2] = f2bf(ldin(seq, base + s2, f32));
      }
      #pragma unroll
      for (int ml = 0; ml < 2; ++ml)
        #pragma unroll
        for (int ht = 0; ht < 4; ++ht)
          #pragma unroll
          for (int r = 0; r < 4; ++r){
            int m = (mh*2+ml)*16 + quad*4 + r;
            int col = cr*64 + ht*16 + col16;
            cw[ml][ht][r] = c0s[m*256 + col];
          }
    }
    __syncthreads();

    for (int t = 0; t < 16; ++t){
      if (is_enc){
        if (tid < 64){
          const int base = (brow0+tid)*64 + t*4;
          ushort_t* xp = &Ap[((tid>>4)*9 + 8)*512 + (tid&15)*8];
          #pragma unroll
          for (int s2 = 0; s2 < 4; ++s2) xp[s2] = f2bf(ldin(seq, base + s2, f32));
        }
        __syncthreads();
      }

      // ---- gate GEMM: [64,288] x [288,1024], wave covers (m-half, 4 gates x 64 cols) ----
      f32x4 acc[2][16];
      #pragma unroll
      for (int i = 0; i < 2; ++i)
        #pragma unroll
        for (int j = 0; j < 16; ++j) acc[i][j] = zero4;
      const int mt0 = mh*2, mt1 = mt0+1;
      for (int kt = 0; kt < 9; ++kt){
        bf16x8 a0 = *(const bf16x8*)&Ap[(mt0*9+kt)*512 + lane*8];
        bf16x8 a1 = *(const bf16x8*)&Ap[(mt1*9+kt)*512 + lane*8];
        #pragma unroll
        for (int g = 0; g < 4; ++g){
          #pragma unroll
          for (int ht = 0; ht < 4; ++ht){
            const int ntg = g*16 + cr*4 + ht;
            bf16x8 bv = *(const bf16x8*)&packW[((ntg*9+kt)*64 + lane)*8];
            acc[0][g*4+ht] = __builtin_amdgcn_mfma_f32_16x16x32_bf16(a0, bv, acc[0][g*4+ht], 0, 0, 0);
            acc[1][g*4+ht] = __builtin_amdgcn_mfma_f32_16x16x32_bf16(a1, bv, acc[1][g*4+ht], 0, 0, 0);
          }
        }
      }
      __syncthreads();   // all A reads done; safe to overwrite h

      // ---- gate nonlinearity + state update (all in-lane: gates share C-layout) ----
      const bool enc_last = is_enc && (t == 15);
      #pragma unroll
      for (int ml = 0; ml < 2; ++ml){
        const int mtg = mh*2 + ml;
        #pragma unroll
        for (int ht = 0; ht < 4; ++ht){
          const int col = cr*64 + ht*16 + col16;
          #pragma unroll
          for (int r = 0; r < 4; ++r){
            float gi = acc[ml][ht][r]    + bia[0][ht];
            float gf = acc[ml][4+ht][r]  + bia[1][ht];
            float gg = acc[ml][8+ht][r]  + bia[2][ht];
            float go = acc[ml][12+ht][r] + bia[3][ht];
            float cn = sigmf_(gf)*cw[ml][ht][r] + sigmf_(gi)*tanhf_(gg);
            float hn = sigmf_(go)*tanhf_(cn);
            cw[ml][ht][r] = cn;
            const int m = mtg*16 + quad*4 + r;
            if (enc_last){
              if (phase == 0){ h0s[m*256+col] = f2bf(hn);  c0s[m*256+col] = cn; }
              else { h0s[m*256+col] = f2bf(bf2f(h0s[m*256+col]) + hn);  c0s[m*256+col] += cn; }
            } else {
              Ap[(mtg*9 + (col>>5))*512 + ((col>>3)&3)*128 + (m&15)*8 + (col&7)] = f2bf(hn);
            }
          }
        }
      }

      if (!is_enc){
        __syncthreads();   // h_t visible for head
        if (wid < 4){      // wave w handles m-tile w (16 rows), 8 MFMAs over K=256
          f32x4 hacc = zero4;
          #pragma unroll
          for (int kt = 0; kt < 8; ++kt){
            bf16x8 a  = *(const bf16x8*)&Ap[(wid*9+kt)*512 + lane*8];
            bf16x8 bv = *(const bf16x8*)&headW[(kt*64+lane)*8];
            hacc = __builtin_amdgcn_mfma_f32_16x16x32_bf16(a, bv, hacc, 0, 0, 0);
          }
          const int s = col16;
          if (phase == 2){
            if (s < 4){
              const float hb = ldin(fcsp_b, s, f32);
              #pragma unroll
              for (int r = 0; r < 4; ++r){
                float v = hacc[r] + hb;
                v = fminf(fmaxf(v, -100.f), 100.f);   // hardtanh(+-100)
                const int m = wid*16 + quad*4 + r;
                const int oi = (brow0+m)*64 + t*4 + s;
                if (f32) outf[oi] = v; else outu[oi] = f2bf(v);      // speed output
                Ap[(wid*9+8)*512 + (m&15)*8 + s] = f2bf(v);          // feedback x_{t+1}
              }
            }
          } else {
            const float addv = (s < 4) ? ldin(embb, s, f32)
                              : ((s < 6) ? ldin(fccr_b, s-4, f32) : 0.f);
            #pragma unroll
            for (int r = 0; r < 4; ++r){
              float v = fmaxf(hacc[r] + addv, 0.f);   // relu
              const float o = __shfl_xor(v, 1, 64);   // pair lanes 4<->5 (logits)
              const int m = wid*16 + quad*4 + r;
              if (s < 4){
                Ap[(wid*9+8)*512 + (m&15)*8 + s] = f2bf(v);          // feedback relu(emb)
              } else if (s < 6){
                const float mx = fmaxf(v, o);
                const float e0 = __expf(v-mx), e1 = __expf(o-mx);
                const float sm = e0/(e0+e1);
                const int oi = 1048576 + (brow0+m)*32 + t*2 + (s-4); // softmax2
                if (f32) outf[oi] = sm; else outu[oi] = f2bf(sm);
              }
            }
          }
        }
        __syncthreads();   // feedback x visible for next gate GEMM
      }
    }
  }
}

extern "C" void kernel_launch(void* const* d_in, const int* in_sizes, int n_in,
                              void* d_out, int out_size, void* d_ws, size_t ws_size,
                              hipStream_t stream) {
  PackArgs pa;
  pa.wih[0]=(const ushort_t*)d_in[2];  pa.whh[0]=(const ushort_t*)d_in[3];
  pa.bih[0]=(const ushort_t*)d_in[4];  pa.bhh[0]=(const ushort_t*)d_in[5];
  pa.wih[1]=(const ushort_t*)d_in[6];  pa.whh[1]=(const ushort_t*)d_in[7];
  pa.bih[1]=(const ushort_t*)d_in[8];  pa.bhh[1]=(const ushort_t*)d_in[9];
  pa.wih[2]=(const ushort_t*)d_in[10]; pa.whh[2]=(const ushort_t*)d_in[11];
  pa.bih[2]=(const ushort_t*)d_in[12]; pa.bhh[2]=(const ushort_t*)d_in[13];
  pa.wih[3]=(const ushort_t*)d_in[14]; pa.whh[3]=(const ushort_t*)d_in[15];
  pa.bih[3]=(const ushort_t*)d_in[16]; pa.bhh[3]=(const ushort_t*)d_in[17];
  pa.fcsp_w=(const ushort_t*)d_in[18];
  pa.fccr_w=(const ushort_t*)d_in[20];
  pa.emb_w =(const ushort_t*)d_in[22];
  pa.ws = (ushort_t*)d_ws;

  hipLaunchKernelGGL(pack_kernel, dim3(4656), dim3(256), 0, stream, pa);
  hipLaunchKernelGGL(pvlstm_main, dim3(256), dim3(512), 0, stream,
      (const ushort_t*)d_ws,
      (const ushort_t*)d_in[0], (const ushort_t*)d_in[1],
      (const ushort_t*)d_in[19], (const ushort_t*)d_in[21], (const ushort_t*)d_in[23],
      d_out);
}